// Round 1
// baseline (993.126 us; speedup 1.0000x reference)
//
#include <hip/hip_runtime.h>
#include <math.h>

#define N_RAYS 2048
#define NSAMP  256
#define NPTS   (N_RAYS * NSAMP)
#define GRIDN  128
#define G2     (GRIDN * GRIDN)
#define G3     (GRIDN * GRIDN * GRIDN)
#define APPC   27
#define FEATC  128
#define K1     150
#define STRIDE 36   // LDS row stride in floats (mult of 4 -> b128; broadcast-friendly banks)

__device__ __forceinline__ void corner_setup(float cx, float cy, float cz,
                                             int& ibase, float* w8) {
  float x = (cx + 1.0f) * 0.5f * 127.0f;
  float y = (cy + 1.0f) * 0.5f * 127.0f;
  float z = (cz + 1.0f) * 0.5f * 127.0f;
  float x0f = fminf(fmaxf(floorf(x), 0.0f), 126.0f);
  float y0f = fminf(fmaxf(floorf(y), 0.0f), 126.0f);
  float z0f = fminf(fmaxf(floorf(z), 0.0f), 126.0f);
  int x0 = (int)x0f, y0 = (int)y0f, z0 = (int)z0f;
  float fx = x - x0f, fy = y - y0f, fz = z - z0f;
  float gx = 1.0f - fx, gy = 1.0f - fy, gz = 1.0f - fz;
  ibase = (z0 * GRIDN + y0) * GRIDN + x0;
  w8[0] = gz * gy * gx; w8[1] = gz * gy * fx;
  w8[2] = gz * fy * gx; w8[3] = gz * fy * fx;
  w8[4] = fz * gy * gx; w8[5] = fz * gy * fx;
  w8[6] = fz * fy * gx; w8[7] = fz * fy * fx;
}

__device__ __forceinline__ float tri_fetch(const float* v, int ibase, const float* w8) {
  return v[ibase]           * w8[0] + v[ibase + 1]           * w8[1]
       + v[ibase + GRIDN]   * w8[2] + v[ibase + GRIDN + 1]   * w8[3]
       + v[ibase + G2]      * w8[4] + v[ibase + G2 + 1]      * w8[5]
       + v[ibase + G2+GRIDN]* w8[6] + v[ibase + G2+GRIDN+1]  * w8[7];
}

// One block per ray: coords, density, alpha, serial cumprod -> weights + acc
__global__ __launch_bounds__(256)
void ray_kernel(const float* __restrict__ rays_o, const float* __restrict__ rays_d,
                const float* __restrict__ dvol,
                float* __restrict__ coords_ws, float* __restrict__ weights_ws,
                float* __restrict__ acc_ws) {
  int r = blockIdx.x;
  int s = threadIdx.x;
  __shared__ float alpha_s[NSAMP];
  float ox = rays_o[r*3+0], oy = rays_o[r*3+1], oz = rays_o[r*3+2];
  float dx = rays_d[r*3+0], dy = rays_d[r*3+1], dz = rays_d[r*3+2];
  float inv = rsqrtf(dx*dx + dy*dy + dz*dz);
  dx *= inv; dy *= inv; dz *= inv;
  float z = 2.0f + (4.0f / 255.0f) * (float)s;
  float px = ox + dx * z, py = oy + dy * z, pz = oz + dz * z;
  float cx = fminf(fmaxf((px + 1.5f) * (2.0f/3.0f) - 1.0f, -1.0f), 1.0f);
  float cy = fminf(fmaxf((py + 1.5f) * (2.0f/3.0f) - 1.0f, -1.0f), 1.0f);
  float cz = fminf(fmaxf((pz + 1.5f) * (2.0f/3.0f) - 1.0f, -1.0f), 1.0f);
  int gp = r * NSAMP + s;
  coords_ws[gp*3+0] = cx; coords_ws[gp*3+1] = cy; coords_ws[gp*3+2] = cz;

  int ibase; float w8[8];
  corner_setup(cx, cy, cz, ibase, w8);
  float sf = tri_fetch(dvol, ibase, w8);
  float xv = sf - 10.0f;  // DENSITY_SHIFT
  float sp = (xv > 0.0f) ? (xv + log1pf(expf(-xv))) : log1pf(expf(xv));
  float alpha = 1.0f - expf(-sp * (100.0f / 255.0f));  // dist*DISTANCE_SCALE = (4/255)*25
  alpha_s[s] = alpha;
  __syncthreads();
  if (s == 0) {
    float T = 1.0f, acc = 0.0f;
    #pragma unroll 4
    for (int i = 0; i < NSAMP; ++i) {
      float a = alpha_s[i];
      float w = a * T;
      alpha_s[i] = w;               // reuse as weights
      acc += w;
      T *= (1.0f - a + 1e-10f);
    }
    acc_ws[r] = acc;
  }
  __syncthreads();
  weights_ws[gp] = alpha_s[s];
}

// One block per 32 samples (all same ray): app trilinear + PE -> MLP -> weighted accum
__global__ __launch_bounds__(256)
void shade_kernel(const float* __restrict__ rays_d, const float* __restrict__ avol,
                  const float* __restrict__ w1, const float* __restrict__ b1,
                  const float* __restrict__ w2, const float* __restrict__ b2,
                  const float* __restrict__ w3, const float* __restrict__ b3,
                  const float* __restrict__ coords_ws, const float* __restrict__ weights_ws,
                  float* __restrict__ rgb_accum) {
  __shared__ __align__(16) float in_lds[K1 * STRIDE];     // [k][p], also reused as h2
  __shared__ __align__(16) float h_lds[FEATC * STRIDE];   // [j][p]
  __shared__ float red[3][32];

  int t = threadIdx.x;
  int p = t & 31;
  int gp0 = blockIdx.x * 32;
  int gp = gp0 + p;
  int r = gp0 >> 8;   // all 32 points in the same ray

  // ---- stage 1: features + positional encoding into in_lds[k][p] ----
  float cx = coords_ws[gp*3+0], cy = coords_ws[gp*3+1], cz = coords_ws[gp*3+2];
  int ibase; float w8[8];
  corner_setup(cx, cy, cz, ibase, w8);
  int cg = t >> 5;  // 0..7
  for (int c = cg; c < APPC; c += 8) {
    float f = tri_fetch(avol + (size_t)c * G3, ibase, w8);
    in_lds[c * STRIDE + p] = f;
    float s1, c1, s2, c2;
    sincosf(f, &s1, &c1);
    sincosf(2.0f * f, &s2, &c2);
    in_lds[(30 + 2*c) * STRIDE + p] = s1;
    in_lds[(31 + 2*c) * STRIDE + p] = s2;
    in_lds[(84 + 2*c) * STRIDE + p] = c1;
    in_lds[(85 + 2*c) * STRIDE + p] = c2;
  }
  if (cg == 0) {
    float dx = rays_d[r*3+0], dy = rays_d[r*3+1], dz = rays_d[r*3+2];
    float inv = rsqrtf(dx*dx + dy*dy + dz*dz);
    dx *= inv; dy *= inv; dz *= inv;
    float vd[3] = {dx, dy, dz};
    in_lds[27 * STRIDE + p] = dx;
    in_lds[28 * STRIDE + p] = dy;
    in_lds[29 * STRIDE + p] = dz;
    for (int d = 0; d < 3; ++d) {
      float s1, c1, s2, c2;
      sincosf(vd[d], &s1, &c1);
      sincosf(2.0f * vd[d], &s2, &c2);
      in_lds[(138 + 2*d) * STRIDE + p] = s1;
      in_lds[(139 + 2*d) * STRIDE + p] = s2;
      in_lds[(144 + 2*d) * STRIDE + p] = c1;
      in_lds[(145 + 2*d) * STRIDE + p] = c2;
    }
  }
  __syncthreads();

  // ---- stage 2: layer 1 (K=150) ----
  int pg = t & 7;      // 8 point-groups of 4
  int jg = t >> 3;     // 32 j-groups of 4
  const float4* w1v = (const float4*)w1;
  float acc[4][4];
  #pragma unroll
  for (int i = 0; i < 4; ++i)
    #pragma unroll
    for (int j = 0; j < 4; ++j) acc[i][j] = 0.0f;
  for (int k = 0; k < K1; ++k) {
    float4 a = *(const float4*)&in_lds[k * STRIDE + pg * 4];
    float4 b = w1v[k * 32 + jg];
    float av[4] = {a.x, a.y, a.z, a.w};
    float bv[4] = {b.x, b.y, b.z, b.w};
    #pragma unroll
    for (int i = 0; i < 4; ++i)
      #pragma unroll
      for (int j = 0; j < 4; ++j) acc[i][j] += av[i] * bv[j];
  }
  {
    float4 bb = ((const float4*)b1)[jg];
    float bbv[4] = {bb.x, bb.y, bb.z, bb.w};
    #pragma unroll
    for (int j = 0; j < 4; ++j) {
      float4 hv;
      hv.x = fmaxf(acc[0][j] + bbv[j], 0.0f);
      hv.y = fmaxf(acc[1][j] + bbv[j], 0.0f);
      hv.z = fmaxf(acc[2][j] + bbv[j], 0.0f);
      hv.w = fmaxf(acc[3][j] + bbv[j], 0.0f);
      *(float4*)&h_lds[(jg * 4 + j) * STRIDE + pg * 4] = hv;
    }
  }
  __syncthreads();

  // ---- layer 2 (K=128), output into in_lds region (h2) ----
  const float4* w2v = (const float4*)w2;
  #pragma unroll
  for (int i = 0; i < 4; ++i)
    #pragma unroll
    for (int j = 0; j < 4; ++j) acc[i][j] = 0.0f;
  for (int k = 0; k < FEATC; ++k) {
    float4 a = *(const float4*)&h_lds[k * STRIDE + pg * 4];
    float4 b = w2v[k * 32 + jg];
    float av[4] = {a.x, a.y, a.z, a.w};
    float bv[4] = {b.x, b.y, b.z, b.w};
    #pragma unroll
    for (int i = 0; i < 4; ++i)
      #pragma unroll
      for (int j = 0; j < 4; ++j) acc[i][j] += av[i] * bv[j];
  }
  {
    float4 bb = ((const float4*)b2)[jg];
    float bbv[4] = {bb.x, bb.y, bb.z, bb.w};
    #pragma unroll
    for (int j = 0; j < 4; ++j) {
      float4 hv;
      hv.x = fmaxf(acc[0][j] + bbv[j], 0.0f);
      hv.y = fmaxf(acc[1][j] + bbv[j], 0.0f);
      hv.z = fmaxf(acc[2][j] + bbv[j], 0.0f);
      hv.w = fmaxf(acc[3][j] + bbv[j], 0.0f);
      *(float4*)&in_lds[(jg * 4 + j) * STRIDE + pg * 4] = hv;
    }
  }
  __syncthreads();

  // ---- layer 3 (128 -> 3) + sigmoid + weighted partial sum ----
  if (t < 96) {
    int pp = t & 31, j = t >> 5;
    float a = b3[j];
    for (int k = 0; k < FEATC; ++k) a += in_lds[k * STRIDE + pp] * w3[k * 3 + j];
    float rgb = 1.0f / (1.0f + expf(-a));
    red[j][pp] = rgb * weights_ws[gp0 + pp];
  }
  __syncthreads();
  if (t < 3) {
    float sum = 0.0f;
    #pragma unroll 4
    for (int i = 0; i < 32; ++i) sum += red[t][i];
    atomicAdd(&rgb_accum[r * 3 + t], sum);
  }
}

__global__ void finish_kernel(const float* __restrict__ rgb_accum,
                              const float* __restrict__ acc_ws,
                              float* __restrict__ out) {
  int i = blockIdx.x * blockDim.x + threadIdx.x;
  if (i < N_RAYS * 3) {
    int r = i / 3;
    float v = rgb_accum[i] + 1.0f - acc_ws[r];
    out[i] = fminf(fmaxf(v, 0.0f), 1.0f);
  }
}

extern "C" void kernel_launch(void* const* d_in, const int* in_sizes, int n_in,
                              void* d_out, int out_size, void* d_ws, size_t ws_size,
                              hipStream_t stream) {
  const float* rays_o = (const float*)d_in[0];
  const float* rays_d = (const float*)d_in[1];
  const float* dvol   = (const float*)d_in[2];
  const float* avol   = (const float*)d_in[3];
  const float* w1     = (const float*)d_in[4];
  const float* b1     = (const float*)d_in[5];
  const float* w2     = (const float*)d_in[6];
  const float* b2     = (const float*)d_in[7];
  const float* w3     = (const float*)d_in[8];
  const float* b3     = (const float*)d_in[9];
  float* out = (float*)d_out;

  float* coords_ws  = (float*)d_ws;              // NPTS*3
  float* weights_ws = coords_ws + (size_t)NPTS * 3;  // NPTS
  float* acc_ws     = weights_ws + NPTS;         // N_RAYS
  float* rgb_accum  = acc_ws + N_RAYS;           // N_RAYS*3

  hipMemsetAsync(rgb_accum, 0, N_RAYS * 3 * sizeof(float), stream);
  ray_kernel<<<N_RAYS, 256, 0, stream>>>(rays_o, rays_d, dvol,
                                         coords_ws, weights_ws, acc_ws);
  shade_kernel<<<NPTS / 32, 256, 0, stream>>>(rays_d, avol, w1, b1, w2, b2, w3, b3,
                                              coords_ws, weights_ws, rgb_accum);
  finish_kernel<<<(N_RAYS * 3 + 255) / 256, 256, 0, stream>>>(rgb_accum, acc_ws, out);
}

// Round 2
// 610.809 us; speedup vs baseline: 1.6259x; 1.6259x over previous
//
#include <hip/hip_runtime.h>
#include <math.h>

#define N_RAYS 2048
#define NSAMP  256
#define NPTS   (N_RAYS * NSAMP)
#define GRIDN  128
#define G2     (GRIDN * GRIDN)
#define G3     (GRIDN * GRIDN * GRIDN)
#define APPC   27
#define CHP    28            // padded channels in transposed volume
#define FEATC  128
#define K1PAD  160           // 150 padded to 160 (5 k-tiles of 32)
#define ASTR   168           // A_lds k-stride (bank-friendly)
#define HSTR   136           // h1_lds k-stride
#define H2STR  132           // h2 stride (aliases A_lds)

typedef __attribute__((ext_vector_type(8))) short short8;
typedef __attribute__((ext_vector_type(4))) float float4v;

__device__ __forceinline__ unsigned short f2bf(float f) {
  unsigned int u = __float_as_uint(f);
  return (unsigned short)((u + 0x7FFFu + ((u >> 16) & 1u)) >> 16);
}
__device__ __forceinline__ float bf2f(unsigned short u) {
  return __uint_as_float(((unsigned int)u) << 16);
}

__device__ __forceinline__ void corner_setup(float cx, float cy, float cz,
                                             int& ibase, float* w8) {
  float x = (cx + 1.0f) * 0.5f * 127.0f;
  float y = (cy + 1.0f) * 0.5f * 127.0f;
  float z = (cz + 1.0f) * 0.5f * 127.0f;
  float x0f = fminf(fmaxf(floorf(x), 0.0f), 126.0f);
  float y0f = fminf(fmaxf(floorf(y), 0.0f), 126.0f);
  float z0f = fminf(fmaxf(floorf(z), 0.0f), 126.0f);
  int x0 = (int)x0f, y0 = (int)y0f, z0 = (int)z0f;
  float fx = x - x0f, fy = y - y0f, fz = z - z0f;
  float gx = 1.0f - fx, gy = 1.0f - fy, gz = 1.0f - fz;
  ibase = (z0 * GRIDN + y0) * GRIDN + x0;
  w8[0] = gz * gy * gx; w8[1] = gz * gy * fx;
  w8[2] = gz * fy * gx; w8[3] = gz * fy * fx;
  w8[4] = fz * gy * gx; w8[5] = fz * gy * fx;
  w8[6] = fz * fy * gx; w8[7] = fz * fy * fx;
}

// ---------------- transpose app volume: [27][z][y][x] f32 -> [z][y][x][28] bf16
__global__ __launch_bounds__(256)
void transpose_kernel(const float* __restrict__ avol, unsigned short* __restrict__ appT) {
  int vi = blockIdx.x * 256 + threadIdx.x;   // 0 .. G3-1
  float v[CHP];
  #pragma unroll
  for (int c = 0; c < APPC; ++c) v[c] = avol[(size_t)c * G3 + vi];
  v[27] = 0.0f;
  unsigned short* dst = appT + (size_t)vi * CHP;
  #pragma unroll
  for (int i = 0; i < 7; ++i) {
    ushort4 o;
    o.x = f2bf(v[4*i+0]); o.y = f2bf(v[4*i+1]);
    o.z = f2bf(v[4*i+2]); o.w = f2bf(v[4*i+3]);
    *(ushort4*)&dst[4*i] = o;
  }
}

// ---------------- weight prep: w1 [150][128] -> w1T bf16 [128][160] (zero-padded k)
//                  w2 [128][128] -> w2T bf16 [128][128]
__global__ __launch_bounds__(256)
void prep_weights(const float* __restrict__ w1, const float* __restrict__ w2,
                  unsigned short* __restrict__ w1T, unsigned short* __restrict__ w2T) {
  int t = blockIdx.x * 256 + threadIdx.x;
  if (t < 128 * K1PAD) {
    int n = t / K1PAD, k = t - n * K1PAD;
    w1T[t] = (k < 150) ? f2bf(w1[k * 128 + n]) : (unsigned short)0;
  } else {
    int i = t - 128 * K1PAD;
    if (i < 128 * 128) {
      int n = i >> 7, k = i & 127;
      w2T[i] = f2bf(w2[k * 128 + n]);
    }
  }
}

// ---------------- ray kernel: alpha + wave-scan cumprod -> weights, acc
__global__ __launch_bounds__(256)
void ray_kernel(const float* __restrict__ rays_o, const float* __restrict__ rays_d,
                const float* __restrict__ dvol,
                float* __restrict__ weights_ws, float* __restrict__ acc_ws) {
  int r = blockIdx.x, s = threadIdx.x;
  int lane = s & 63, wv = s >> 6;
  float ox = rays_o[r*3+0], oy = rays_o[r*3+1], oz = rays_o[r*3+2];
  float dx = rays_d[r*3+0], dy = rays_d[r*3+1], dz = rays_d[r*3+2];
  float inv = rsqrtf(dx*dx + dy*dy + dz*dz);
  dx *= inv; dy *= inv; dz *= inv;
  float z = 2.0f + (4.0f / 255.0f) * (float)s;
  float px = ox + dx * z, py = oy + dy * z, pz = oz + dz * z;
  float cx = fminf(fmaxf((px + 1.5f) * (2.0f/3.0f) - 1.0f, -1.0f), 1.0f);
  float cy = fminf(fmaxf((py + 1.5f) * (2.0f/3.0f) - 1.0f, -1.0f), 1.0f);
  float cz = fminf(fmaxf((pz + 1.5f) * (2.0f/3.0f) - 1.0f, -1.0f), 1.0f);
  int ibase; float w8[8];
  corner_setup(cx, cy, cz, ibase, w8);
  float sf = dvol[ibase]            * w8[0] + dvol[ibase + 1]            * w8[1]
           + dvol[ibase + GRIDN]    * w8[2] + dvol[ibase + GRIDN + 1]    * w8[3]
           + dvol[ibase + G2]       * w8[4] + dvol[ibase + G2 + 1]       * w8[5]
           + dvol[ibase + G2+GRIDN] * w8[6] + dvol[ibase + G2+GRIDN+1]   * w8[7];
  float xv = sf - 10.0f;
  float sp = (xv > 0.0f) ? (xv + log1pf(expf(-xv))) : log1pf(expf(xv));
  float alpha = 1.0f - expf(-sp * (100.0f / 255.0f));

  // wave-level inclusive prefix product of t = 1 - a + 1e-10
  float tt = 1.0f - alpha + 1e-10f;
  float p = tt;
  #pragma unroll
  for (int d = 1; d < 64; d <<= 1) {
    float v = __shfl_up(p, d);
    if (lane >= d) p *= v;
  }
  __shared__ float wtot[4], wacc[4];
  if (lane == 63) wtot[wv] = p;
  __syncthreads();
  float pref = 1.0f;
  #pragma unroll
  for (int w2i = 0; w2i < 3; ++w2i) if (w2i < wv) pref *= wtot[w2i];
  float ex = __shfl_up(p, 1);
  if (lane == 0) ex = 1.0f;
  float T = pref * ex;
  float wgt = alpha * T;
  weights_ws[r * NSAMP + s] = wgt;
  float sum = wgt;
  #pragma unroll
  for (int d = 32; d; d >>= 1) sum += __shfl_xor(sum, d);
  if (lane == 0) wacc[wv] = sum;
  __syncthreads();
  if (s == 0) acc_ws[r] = wacc[0] + wacc[1] + wacc[2] + wacc[3];
}

// ---------------- shade: gather+PE -> MFMA MLP -> weighted rgb accumulate
// 64 points per block, 256 threads (4 waves). Early-exit on dead transmittance.
template <bool USET>
__global__ __launch_bounds__(256)
void shade_kernel(const float* __restrict__ rays_o, const float* __restrict__ rays_d,
                  const float* __restrict__ avol, const unsigned short* __restrict__ appT,
                  const unsigned short* __restrict__ w1T, const unsigned short* __restrict__ w2T,
                  const float* __restrict__ b1, const float* __restrict__ b2,
                  const float* __restrict__ w3, const float* __restrict__ b3,
                  const float* __restrict__ weights_ws, float* __restrict__ rgb_accum) {
  __shared__ unsigned short A_lds[64 * ASTR];   // 21504 B, reused as h2 (stride 132)
  __shared__ unsigned short h1_lds[64 * HSTR];  // 17408 B
  __shared__ float red[192];
  __shared__ float blocksum;

  int t = threadIdx.x;
  int gp0 = blockIdx.x * 64;
  int r = gp0 >> 8;

  // ---- early exit if this 64-sample chunk has ~zero weight ----
  if (t < 64) {
    float s = weights_ws[gp0 + t];
    #pragma unroll
    for (int d = 32; d; d >>= 1) s += __shfl_xor(s, d);
    if (t == 0) blocksum = s;
  }
  __syncthreads();
  if (blocksum < 1e-5f) return;

  // ---- gather + positional encoding ----
  {
    int q = t & 3, pt = t >> 2;
    int gp = gp0 + pt, s = gp & 255;
    float ox = rays_o[r*3+0], oy = rays_o[r*3+1], oz = rays_o[r*3+2];
    float dx = rays_d[r*3+0], dy = rays_d[r*3+1], dz = rays_d[r*3+2];
    float inv = rsqrtf(dx*dx + dy*dy + dz*dz);
    dx *= inv; dy *= inv; dz *= inv;
    float z = 2.0f + (4.0f / 255.0f) * (float)s;
    float px = ox + dx * z, py = oy + dy * z, pz = oz + dz * z;
    float cx = fminf(fmaxf((px + 1.5f) * (2.0f/3.0f) - 1.0f, -1.0f), 1.0f);
    float cy = fminf(fmaxf((py + 1.5f) * (2.0f/3.0f) - 1.0f, -1.0f), 1.0f);
    float cz = fminf(fmaxf((pz + 1.5f) * (2.0f/3.0f) - 1.0f, -1.0f), 1.0f);
    int ibase; float w8[8];
    corner_setup(cx, cy, cz, ibase, w8);

    // lane q covers x-adjacent corner pair (2q, 2q+1)
    int vi = ibase + (q >> 1) * G2 + (q & 1) * GRIDN;
    float wA = w8[2*q], wB = w8[2*q+1];
    float part[27];
    if (USET) {
      const ushort4* c0 = (const ushort4*)(appT + (size_t)vi * CHP);
      const ushort4* c1 = (const ushort4*)(appT + (size_t)(vi + 1) * CHP);
      ushort4 a[7], b[7];
      #pragma unroll
      for (int i = 0; i < 7; ++i) { a[i] = c0[i]; b[i] = c1[i]; }
      #pragma unroll
      for (int c = 0; c < 27; ++c) {
        unsigned short ua = (&a[c >> 2].x)[c & 3];
        unsigned short ub = (&b[c >> 2].x)[c & 3];
        part[c] = wA * bf2f(ua) + wB * bf2f(ub);
      }
    } else {
      #pragma unroll
      for (int c = 0; c < 27; ++c) {
        const float* base = avol + (size_t)c * G3 + vi;
        part[c] = wA * base[0] + wB * base[1];
      }
    }
    // butterfly over the 4-lane quad -> full trilinear sum in every lane
    #pragma unroll
    for (int c = 0; c < 27; ++c) {
      float v = part[c];
      v += __shfl_xor(v, 1);
      v += __shfl_xor(v, 2);
      part[c] = v;
    }
    // lane q takes channels [7q, 7q+7) (q==3: 6 valid)
    float f[7];
    #pragma unroll
    for (int j = 0; j < 7; ++j) {
      float vlo = (q & 1) ? part[7 + j] : part[j];
      float vhi = (q & 1) ? part[(21 + j < 27) ? 21 + j : 26] : part[14 + j];
      f[j] = (q & 2) ? vhi : vlo;
    }
    unsigned short* Arow = A_lds + pt * ASTR;
    int cbase = 7 * q;
    #pragma unroll
    for (int j = 0; j < 7; ++j) {
      int c = cbase + j;
      if (c < 27) {
        float fv = f[j];
        Arow[c] = f2bf(fv);
        float s1 = __sinf(fv),      c1 = __cosf(fv);
        float s2 = __sinf(2.0f*fv), c2 = __cosf(2.0f*fv);
        Arow[30 + 2*c] = f2bf(s1); Arow[31 + 2*c] = f2bf(s2);
        Arow[84 + 2*c] = f2bf(c1); Arow[85 + 2*c] = f2bf(c2);
      }
    }
    if (q == 3) {
      float vd[3] = {dx, dy, dz};
      #pragma unroll
      for (int d = 0; d < 3; ++d) {
        Arow[27 + d] = f2bf(vd[d]);
        float s1 = __sinf(vd[d]),      c1 = __cosf(vd[d]);
        float s2 = __sinf(2.0f*vd[d]), c2 = __cosf(2.0f*vd[d]);
        Arow[138 + 2*d] = f2bf(s1); Arow[139 + 2*d] = f2bf(s2);
        Arow[144 + 2*d] = f2bf(c1); Arow[145 + 2*d] = f2bf(c2);
      }
    }
    if (q == 1) {   // zero k-padding cols 150..159
      #pragma unroll
      for (int i = 0; i < 5; ++i) *(unsigned int*)&Arow[150 + 2*i] = 0u;
    }
  }
  __syncthreads();

  // ---- MFMA MLP ----
  int lane = t & 63, wv = t >> 6;
  int nlo = lane & 15;          // n (col) / m-row selector within tile
  int koff = (lane >> 4) * 8;   // k chunk
  int mrow = wv * 16 + nlo;     // this wave's A rows

  // layer 1: A [64 x 160] bf16 (LDS) x w1T [128][160] -> h1 [64 x 128]
  short8 a1[5];
  #pragma unroll
  for (int kt = 0; kt < 5; ++kt)
    a1[kt] = *(const short8*)&A_lds[mrow * ASTR + kt * 32 + koff];
  #pragma unroll
  for (int nt = 0; nt < 8; ++nt) {
    float4v acc = {0.f, 0.f, 0.f, 0.f};
    #pragma unroll
    for (int kt = 0; kt < 5; ++kt) {
      short8 b = *(const short8*)&w1T[(nt * 16 + nlo) * K1PAD + kt * 32 + koff];
      acc = __builtin_amdgcn_mfma_f32_16x16x32_bf16(a1[kt], b, acc, 0, 0, 0);
    }
    float bv = b1[nt * 16 + nlo];
    #pragma unroll
    for (int rg = 0; rg < 4; ++rg) {
      int m = wv * 16 + (lane >> 4) * 4 + rg;
      float hv = fmaxf(acc[rg] + bv, 0.0f);
      h1_lds[m * HSTR + nt * 16 + nlo] = f2bf(hv);
    }
  }
  __syncthreads();

  // layer 2: h1 x w2T -> h2 (bf16, aliases A_lds, stride 132)
  short8 a2[4];
  #pragma unroll
  for (int kt = 0; kt < 4; ++kt)
    a2[kt] = *(const short8*)&h1_lds[mrow * HSTR + kt * 32 + koff];
  unsigned short* h2 = A_lds;
  #pragma unroll
  for (int nt = 0; nt < 8; ++nt) {
    float4v acc = {0.f, 0.f, 0.f, 0.f};
    #pragma unroll
    for (int kt = 0; kt < 4; ++kt) {
      short8 b = *(const short8*)&w2T[(nt * 16 + nlo) * FEATC + kt * 32 + koff];
      acc = __builtin_amdgcn_mfma_f32_16x16x32_bf16(a2[kt], b, acc, 0, 0, 0);
    }
    float bv = b2[nt * 16 + nlo];
    #pragma unroll
    for (int rg = 0; rg < 4; ++rg) {
      int m = wv * 16 + (lane >> 4) * 4 + rg;
      float hv = fmaxf(acc[rg] + bv, 0.0f);
      h2[m * H2STR + nt * 16 + nlo] = f2bf(hv);
    }
  }
  __syncthreads();

  // layer 3: 128 -> 3, sigmoid, weight
  if (t < 192) {
    int j = t >> 6, pp = t & 63;
    const unsigned short* h2row = h2 + pp * H2STR;
    float sum = b3[j];
    #pragma unroll
    for (int k = 0; k < FEATC; k += 4) {
      ushort4 hv = *(const ushort4*)&h2row[k];
      sum += bf2f(hv.x) * w3[(k+0)*3 + j] + bf2f(hv.y) * w3[(k+1)*3 + j]
           + bf2f(hv.z) * w3[(k+2)*3 + j] + bf2f(hv.w) * w3[(k+3)*3 + j];
    }
    float rgbv = 1.0f / (1.0f + __expf(-sum));
    red[j * 64 + pp] = rgbv * weights_ws[gp0 + pp];
  }
  __syncthreads();
  if (t < 3) {
    float sum = 0.0f;
    #pragma unroll 4
    for (int i = 0; i < 64; ++i) sum += red[t * 64 + i];
    atomicAdd(&rgb_accum[r * 3 + t], sum);
  }
}

__global__ void finish_kernel(const float* __restrict__ rgb_accum,
                              const float* __restrict__ acc_ws,
                              float* __restrict__ out) {
  int i = blockIdx.x * blockDim.x + threadIdx.x;
  if (i < N_RAYS * 3) {
    int r = i / 3;
    float v = rgb_accum[i] + 1.0f - acc_ws[r];
    out[i] = fminf(fmaxf(v, 0.0f), 1.0f);
  }
}

extern "C" void kernel_launch(void* const* d_in, const int* in_sizes, int n_in,
                              void* d_out, int out_size, void* d_ws, size_t ws_size,
                              hipStream_t stream) {
  const float* rays_o = (const float*)d_in[0];
  const float* rays_d = (const float*)d_in[1];
  const float* dvol   = (const float*)d_in[2];
  const float* avol   = (const float*)d_in[3];
  const float* w1     = (const float*)d_in[4];
  const float* b1     = (const float*)d_in[5];
  const float* w2     = (const float*)d_in[6];
  const float* b2     = (const float*)d_in[7];
  const float* w3     = (const float*)d_in[8];
  const float* b3     = (const float*)d_in[9];
  float* out = (float*)d_out;

  float* weights_ws = (float*)d_ws;                         // NPTS
  float* acc_ws     = weights_ws + NPTS;                    // 2048
  float* rgb_accum  = acc_ws + N_RAYS;                      // 6144
  unsigned short* w1T = (unsigned short*)(rgb_accum + N_RAYS * 3);  // 128*160
  unsigned short* w2T = w1T + 128 * K1PAD;                  // 128*128
  unsigned short* appT = w2T + 128 * 128;                   // G3*28 bf16

  size_t fixed_bytes = (size_t)(NPTS + N_RAYS + N_RAYS * 3) * 4
                     + (size_t)(128 * K1PAD + 128 * 128) * 2;
  size_t need = fixed_bytes + (size_t)G3 * CHP * 2;
  bool uset = ws_size >= need;

  hipMemsetAsync(rgb_accum, 0, N_RAYS * 3 * sizeof(float), stream);
  prep_weights<<<(128 * K1PAD + 128 * 128 + 255) / 256, 256, 0, stream>>>(w1, w2, w1T, w2T);
  if (uset)
    transpose_kernel<<<G3 / 256, 256, 0, stream>>>(avol, appT);
  ray_kernel<<<N_RAYS, 256, 0, stream>>>(rays_o, rays_d, dvol, weights_ws, acc_ws);
  if (uset)
    shade_kernel<true><<<NPTS / 64, 256, 0, stream>>>(rays_o, rays_d, avol, appT, w1T, w2T,
                                                      b1, b2, w3, b3, weights_ws, rgb_accum);
  else
    shade_kernel<false><<<NPTS / 64, 256, 0, stream>>>(rays_o, rays_d, avol, appT, w1T, w2T,
                                                       b1, b2, w3, b3, weights_ws, rgb_accum);
  finish_kernel<<<(N_RAYS * 3 + 255) / 256, 256, 0, stream>>>(rgb_accum, acc_ws, out);
}

// Round 3
// 513.447 us; speedup vs baseline: 1.9342x; 1.1896x over previous
//
#include <hip/hip_runtime.h>
#include <math.h>

#define N_RAYS 2048
#define NSAMP  256
#define NPTS   (N_RAYS * NSAMP)
#define NCHUNK (NPTS / 64)
#define GRIDN  128
#define G2     (GRIDN * GRIDN)
#define G3     (GRIDN * GRIDN * GRIDN)
#define APPC   27
#define CHP    28            // padded channels in transposed volume
#define FEATC  128
#define K1PAD  160           // 150 padded to 160 (5 k-tiles of 32)
#define ASTR   168           // A_lds k-stride
#define HSTR   136           // h1_lds k-stride
#define H2STR  132           // h2 stride (aliases A_lds)

typedef __attribute__((ext_vector_type(8))) short short8;
typedef __attribute__((ext_vector_type(4))) float float4v;

__device__ __forceinline__ unsigned short f2bf(float f) {
  unsigned int u = __float_as_uint(f);
  return (unsigned short)((u + 0x7FFFu + ((u >> 16) & 1u)) >> 16);
}
__device__ __forceinline__ float bf2f(unsigned short u) {
  return __uint_as_float(((unsigned int)u) << 16);
}

__device__ __forceinline__ void corner_setup(float cx, float cy, float cz,
                                             int& ibase, float* w8) {
  float x = (cx + 1.0f) * 0.5f * 127.0f;
  float y = (cy + 1.0f) * 0.5f * 127.0f;
  float z = (cz + 1.0f) * 0.5f * 127.0f;
  float x0f = fminf(fmaxf(floorf(x), 0.0f), 126.0f);
  float y0f = fminf(fmaxf(floorf(y), 0.0f), 126.0f);
  float z0f = fminf(fmaxf(floorf(z), 0.0f), 126.0f);
  int x0 = (int)x0f, y0 = (int)y0f, z0 = (int)z0f;
  float fx = x - x0f, fy = y - y0f, fz = z - z0f;
  float gx = 1.0f - fx, gy = 1.0f - fy, gz = 1.0f - fz;
  ibase = (z0 * GRIDN + y0) * GRIDN + x0;
  w8[0] = gz * gy * gx; w8[1] = gz * gy * fx;
  w8[2] = gz * fy * gx; w8[3] = gz * fy * fx;
  w8[4] = fz * gy * gx; w8[5] = fz * gy * fx;
  w8[6] = fz * fy * gx; w8[7] = fz * fy * fx;
}

// ---------------- transpose app volume: [27][z][y][x] f32 -> [z][y][x][28] bf16
// 2 voxels per thread, float2 loads.
__global__ __launch_bounds__(256)
void transpose_kernel(const float* __restrict__ avol, unsigned short* __restrict__ appT) {
  int v0 = (blockIdx.x * 256 + threadIdx.x) * 2;
  float2 v[APPC];
  #pragma unroll
  for (int c = 0; c < APPC; ++c) v[c] = *(const float2*)&avol[(size_t)c * G3 + v0];
  unsigned short* dst = appT + (size_t)v0 * CHP;
  #pragma unroll
  for (int i = 0; i < 7; ++i) {
    ushort4 o;
    o.x = f2bf(v[4*i+0].x); o.y = f2bf(v[4*i+1].x);
    o.z = (4*i+2 < APPC) ? f2bf(v[4*i+2].x) : (unsigned short)0;
    o.w = (4*i+3 < APPC) ? f2bf(v[4*i+3].x) : (unsigned short)0;
    *(ushort4*)&dst[4*i] = o;
  }
  #pragma unroll
  for (int i = 0; i < 7; ++i) {
    ushort4 o;
    o.x = f2bf(v[4*i+0].y); o.y = f2bf(v[4*i+1].y);
    o.z = (4*i+2 < APPC) ? f2bf(v[4*i+2].y) : (unsigned short)0;
    o.w = (4*i+3 < APPC) ? f2bf(v[4*i+3].y) : (unsigned short)0;
    *(ushort4*)&dst[CHP + 4*i] = o;
  }
}

// ---------------- weight prep
__global__ __launch_bounds__(256)
void prep_weights(const float* __restrict__ w1, const float* __restrict__ w2,
                  unsigned short* __restrict__ w1T, unsigned short* __restrict__ w2T) {
  int t = blockIdx.x * 256 + threadIdx.x;
  if (t < 128 * K1PAD) {
    int n = t / K1PAD, k = t - n * K1PAD;
    w1T[t] = (k < 150) ? f2bf(w1[k * 128 + n]) : (unsigned short)0;
  } else {
    int i = t - 128 * K1PAD;
    if (i < 128 * 128) {
      int n = i >> 7, k = i & 127;
      w2T[i] = f2bf(w2[k * 128 + n]);
    }
  }
}

// ---------------- ray kernel: alpha + wave-scan cumprod -> weights, acc, worklist
__global__ __launch_bounds__(256)
void ray_kernel(const float* __restrict__ rays_o, const float* __restrict__ rays_d,
                const float* __restrict__ dvol,
                float* __restrict__ weights_ws, float* __restrict__ acc_ws,
                int* __restrict__ count, int* __restrict__ worklist) {
  int r = blockIdx.x, s = threadIdx.x;
  int lane = s & 63, wv = s >> 6;
  float ox = rays_o[r*3+0], oy = rays_o[r*3+1], oz = rays_o[r*3+2];
  float dx = rays_d[r*3+0], dy = rays_d[r*3+1], dz = rays_d[r*3+2];
  float inv = rsqrtf(dx*dx + dy*dy + dz*dz);
  dx *= inv; dy *= inv; dz *= inv;
  float z = 2.0f + (4.0f / 255.0f) * (float)s;
  float px = ox + dx * z, py = oy + dy * z, pz = oz + dz * z;
  float cx = fminf(fmaxf((px + 1.5f) * (2.0f/3.0f) - 1.0f, -1.0f), 1.0f);
  float cy = fminf(fmaxf((py + 1.5f) * (2.0f/3.0f) - 1.0f, -1.0f), 1.0f);
  float cz = fminf(fmaxf((pz + 1.5f) * (2.0f/3.0f) - 1.0f, -1.0f), 1.0f);
  int ibase; float w8[8];
  corner_setup(cx, cy, cz, ibase, w8);
  float sf = dvol[ibase]            * w8[0] + dvol[ibase + 1]            * w8[1]
           + dvol[ibase + GRIDN]    * w8[2] + dvol[ibase + GRIDN + 1]    * w8[3]
           + dvol[ibase + G2]       * w8[4] + dvol[ibase + G2 + 1]       * w8[5]
           + dvol[ibase + G2+GRIDN] * w8[6] + dvol[ibase + G2+GRIDN+1]   * w8[7];
  float xv = sf - 10.0f;
  float sp = (xv > 0.0f) ? (xv + log1pf(expf(-xv))) : log1pf(expf(xv));
  float alpha = 1.0f - expf(-sp * (100.0f / 255.0f));

  // wave-level inclusive prefix product of (1 - a + 1e-10)
  float tt = 1.0f - alpha + 1e-10f;
  float p = tt;
  #pragma unroll
  for (int d = 1; d < 64; d <<= 1) {
    float v = __shfl_up(p, d);
    if (lane >= d) p *= v;
  }
  __shared__ float wtot[4], wacc[4];
  if (lane == 63) wtot[wv] = p;
  __syncthreads();
  float pref = 1.0f;
  #pragma unroll
  for (int w2i = 0; w2i < 3; ++w2i) if (w2i < wv) pref *= wtot[w2i];
  float ex = __shfl_up(p, 1);
  if (lane == 0) ex = 1.0f;
  float T = pref * ex;
  float wgt = alpha * T;
  weights_ws[r * NSAMP + s] = wgt;
  float sum = wgt;
  #pragma unroll
  for (int d = 32; d; d >>= 1) sum += __shfl_xor(sum, d);
  if (lane == 0) {
    wacc[wv] = sum;
    if (sum >= 1e-5f) {                    // live chunk -> enqueue
      int pos = atomicAdd(count, 1);
      worklist[pos] = r * 4 + wv;
    }
  }
  __syncthreads();
  if (s == 0) acc_ws[r] = wacc[0] + wacc[1] + wacc[2] + wacc[3];
}

// ---------------- persistent shade over compacted worklist
template <bool USET>
__global__ __launch_bounds__(256)
void shade_kernel(const float* __restrict__ rays_o, const float* __restrict__ rays_d,
                  const float* __restrict__ avol, const unsigned short* __restrict__ appT,
                  const unsigned short* __restrict__ w1T, const unsigned short* __restrict__ w2T,
                  const float* __restrict__ b1, const float* __restrict__ b2,
                  const float* __restrict__ w3, const float* __restrict__ b3,
                  const float* __restrict__ weights_ws, float* __restrict__ rgb_accum,
                  const int* __restrict__ count, int* __restrict__ work_ctr,
                  const int* __restrict__ worklist) {
  __shared__ unsigned short A_lds[64 * ASTR];   // reused as h2 (stride 132)
  __shared__ unsigned short h1_lds[64 * HSTR];
  __shared__ int s_idx, s_n;

  int t = threadIdx.x;
  int lane = t & 63, wv = t >> 6;

  if (t == 0) s_n = *count;

  for (;;) {
    __syncthreads();
    if (t == 0) s_idx = atomicAdd(work_ctr, 1);
    __syncthreads();
    if (s_idx >= s_n) break;
    int chunk = worklist[s_idx];
    int gp0 = chunk * 64;
    int r = gp0 >> 8;

    // ---- gather + positional encoding ----
    {
      int q = t & 3, pt = t >> 2;
      int gp = gp0 + pt, s = gp & 255;
      float ox = rays_o[r*3+0], oy = rays_o[r*3+1], oz = rays_o[r*3+2];
      float dx = rays_d[r*3+0], dy = rays_d[r*3+1], dz = rays_d[r*3+2];
      float inv = rsqrtf(dx*dx + dy*dy + dz*dz);
      dx *= inv; dy *= inv; dz *= inv;
      float z = 2.0f + (4.0f / 255.0f) * (float)s;
      float px = ox + dx * z, py = oy + dy * z, pz = oz + dz * z;
      float cx = fminf(fmaxf((px + 1.5f) * (2.0f/3.0f) - 1.0f, -1.0f), 1.0f);
      float cy = fminf(fmaxf((py + 1.5f) * (2.0f/3.0f) - 1.0f, -1.0f), 1.0f);
      float cz = fminf(fmaxf((pz + 1.5f) * (2.0f/3.0f) - 1.0f, -1.0f), 1.0f);
      int ibase; float w8[8];
      corner_setup(cx, cy, cz, ibase, w8);

      int vi = ibase + (q >> 1) * G2 + (q & 1) * GRIDN;
      float wA = w8[2*q], wB = w8[2*q+1];
      float part[27];
      if (USET) {
        const ushort4* c0 = (const ushort4*)(appT + (size_t)vi * CHP);
        const ushort4* c1 = (const ushort4*)(appT + (size_t)(vi + 1) * CHP);
        ushort4 a[7], b[7];
        #pragma unroll
        for (int i = 0; i < 7; ++i) { a[i] = c0[i]; b[i] = c1[i]; }
        #pragma unroll
        for (int c = 0; c < 27; ++c) {
          unsigned short ua = (&a[c >> 2].x)[c & 3];
          unsigned short ub = (&b[c >> 2].x)[c & 3];
          part[c] = wA * bf2f(ua) + wB * bf2f(ub);
        }
      } else {
        #pragma unroll
        for (int c = 0; c < 27; ++c) {
          const float* base = avol + (size_t)c * G3 + vi;
          part[c] = wA * base[0] + wB * base[1];
        }
      }
      #pragma unroll
      for (int c = 0; c < 27; ++c) {
        float v = part[c];
        v += __shfl_xor(v, 1);
        v += __shfl_xor(v, 2);
        part[c] = v;
      }
      float f[7];
      #pragma unroll
      for (int j = 0; j < 7; ++j) {
        float vlo = (q & 1) ? part[7 + j] : part[j];
        float vhi = (q & 1) ? part[(21 + j < 27) ? 21 + j : 26] : part[14 + j];
        f[j] = (q & 2) ? vhi : vlo;
      }
      unsigned short* Arow = A_lds + pt * ASTR;
      int cbase = 7 * q;
      #pragma unroll
      for (int j = 0; j < 7; ++j) {
        int c = cbase + j;
        if (c < 27) {
          float fv = f[j];
          Arow[c] = f2bf(fv);
          float s1 = __sinf(fv),      c1 = __cosf(fv);
          float s2 = __sinf(2.0f*fv), c2 = __cosf(2.0f*fv);
          Arow[30 + 2*c] = f2bf(s1); Arow[31 + 2*c] = f2bf(s2);
          Arow[84 + 2*c] = f2bf(c1); Arow[85 + 2*c] = f2bf(c2);
        }
      }
      if (q == 3) {
        float vd[3] = {dx, dy, dz};
        #pragma unroll
        for (int d = 0; d < 3; ++d) {
          Arow[27 + d] = f2bf(vd[d]);
          float s1 = __sinf(vd[d]),      c1 = __cosf(vd[d]);
          float s2 = __sinf(2.0f*vd[d]), c2 = __cosf(2.0f*vd[d]);
          Arow[138 + 2*d] = f2bf(s1); Arow[139 + 2*d] = f2bf(s2);
          Arow[144 + 2*d] = f2bf(c1); Arow[145 + 2*d] = f2bf(c2);
        }
      }
      if (q == 1) {
        #pragma unroll
        for (int i = 0; i < 5; ++i) *(unsigned int*)&Arow[150 + 2*i] = 0u;
      }
    }
    __syncthreads();

    // ---- MFMA MLP ----
    int nlo = lane & 15;
    int koff = (lane >> 4) * 8;
    int mrow = wv * 16 + nlo;

    short8 a1[5];
    #pragma unroll
    for (int kt = 0; kt < 5; ++kt)
      a1[kt] = *(const short8*)&A_lds[mrow * ASTR + kt * 32 + koff];
    #pragma unroll
    for (int nt = 0; nt < 8; ++nt) {
      float4v acc = {0.f, 0.f, 0.f, 0.f};
      #pragma unroll
      for (int kt = 0; kt < 5; ++kt) {
        short8 b = *(const short8*)&w1T[(nt * 16 + nlo) * K1PAD + kt * 32 + koff];
        acc = __builtin_amdgcn_mfma_f32_16x16x32_bf16(a1[kt], b, acc, 0, 0, 0);
      }
      float bv = b1[nt * 16 + nlo];
      #pragma unroll
      for (int rg = 0; rg < 4; ++rg) {
        int m = wv * 16 + (lane >> 4) * 4 + rg;
        float hv = fmaxf(acc[rg] + bv, 0.0f);
        h1_lds[m * HSTR + nt * 16 + nlo] = f2bf(hv);
      }
    }
    __syncthreads();

    short8 a2[4];
    #pragma unroll
    for (int kt = 0; kt < 4; ++kt)
      a2[kt] = *(const short8*)&h1_lds[mrow * HSTR + kt * 32 + koff];
    unsigned short* h2 = A_lds;
    #pragma unroll
    for (int nt = 0; nt < 8; ++nt) {
      float4v acc = {0.f, 0.f, 0.f, 0.f};
      #pragma unroll
      for (int kt = 0; kt < 4; ++kt) {
        short8 b = *(const short8*)&w2T[(nt * 16 + nlo) * FEATC + kt * 32 + koff];
        acc = __builtin_amdgcn_mfma_f32_16x16x32_bf16(a2[kt], b, acc, 0, 0, 0);
      }
      float bv = b2[nt * 16 + nlo];
      #pragma unroll
      for (int rg = 0; rg < 4; ++rg) {
        int m = wv * 16 + (lane >> 4) * 4 + rg;
        float hv = fmaxf(acc[rg] + bv, 0.0f);
        h2[m * H2STR + nt * 16 + nlo] = f2bf(hv);
      }
    }
    __syncthreads();

    // ---- layer 3 (128 -> 3) + sigmoid + in-wave weighted reduce ----
    if (wv < 3) {
      int j = wv, pp = lane;
      const unsigned short* h2row = h2 + pp * H2STR;
      float sum = b3[j];
      #pragma unroll
      for (int k = 0; k < FEATC; k += 4) {
        ushort4 hv = *(const ushort4*)&h2row[k];
        sum += bf2f(hv.x) * w3[(k+0)*3 + j] + bf2f(hv.y) * w3[(k+1)*3 + j]
             + bf2f(hv.z) * w3[(k+2)*3 + j] + bf2f(hv.w) * w3[(k+3)*3 + j];
      }
      float val = (1.0f / (1.0f + __expf(-sum))) * weights_ws[gp0 + pp];
      #pragma unroll
      for (int d = 32; d; d >>= 1) val += __shfl_xor(val, d);
      if (pp == 0) atomicAdd(&rgb_accum[r * 3 + j], val);
    }
  }
}

__global__ void finish_kernel(const float* __restrict__ rgb_accum,
                              const float* __restrict__ acc_ws,
                              float* __restrict__ out) {
  int i = blockIdx.x * blockDim.x + threadIdx.x;
  if (i < N_RAYS * 3) {
    int r = i / 3;
    float v = rgb_accum[i] + 1.0f - acc_ws[r];
    out[i] = fminf(fmaxf(v, 0.0f), 1.0f);
  }
}

extern "C" void kernel_launch(void* const* d_in, const int* in_sizes, int n_in,
                              void* d_out, int out_size, void* d_ws, size_t ws_size,
                              hipStream_t stream) {
  const float* rays_o = (const float*)d_in[0];
  const float* rays_d = (const float*)d_in[1];
  const float* dvol   = (const float*)d_in[2];
  const float* avol   = (const float*)d_in[3];
  const float* w1     = (const float*)d_in[4];
  const float* b1     = (const float*)d_in[5];
  const float* w2     = (const float*)d_in[6];
  const float* b2     = (const float*)d_in[7];
  const float* w3     = (const float*)d_in[8];
  const float* b3     = (const float*)d_in[9];
  float* out = (float*)d_out;

  float* weights_ws = (float*)d_ws;                         // NPTS
  float* acc_ws     = weights_ws + NPTS;                    // 2048
  float* rgb_accum  = acc_ws + N_RAYS;                      // 6144
  int*   count      = (int*)(rgb_accum + N_RAYS * 3);       // 1
  int*   work_ctr   = count + 1;                            // 1
  int*   worklist   = work_ctr + 1;                         // NCHUNK
  unsigned short* w1T = (unsigned short*)(worklist + NCHUNK);
  unsigned short* w2T = w1T + 128 * K1PAD;
  unsigned short* appT = w2T + 128 * 128;

  size_t fixed_bytes = (size_t)(NPTS + N_RAYS + N_RAYS * 3 + 2 + NCHUNK) * 4
                     + (size_t)(128 * K1PAD + 128 * 128) * 2;
  size_t need = fixed_bytes + (size_t)G3 * CHP * 2;
  bool uset = ws_size >= need;

  // zero rgb_accum + count + work_ctr in one memset
  hipMemsetAsync(rgb_accum, 0, (N_RAYS * 3 + 2) * sizeof(float), stream);
  prep_weights<<<(128 * K1PAD + 128 * 128 + 255) / 256, 256, 0, stream>>>(w1, w2, w1T, w2T);
  if (uset)
    transpose_kernel<<<G3 / 512, 256, 0, stream>>>(avol, appT);
  ray_kernel<<<N_RAYS, 256, 0, stream>>>(rays_o, rays_d, dvol, weights_ws, acc_ws,
                                         count, worklist);
  if (uset)
    shade_kernel<true><<<1024, 256, 0, stream>>>(rays_o, rays_d, avol, appT, w1T, w2T,
                                                 b1, b2, w3, b3, weights_ws, rgb_accum,
                                                 count, work_ctr, worklist);
  else
    shade_kernel<false><<<1024, 256, 0, stream>>>(rays_o, rays_d, avol, appT, w1T, w2T,
                                                  b1, b2, w3, b3, weights_ws, rgb_accum,
                                                  count, work_ctr, worklist);
  finish_kernel<<<(N_RAYS * 3 + 255) / 256, 256, 0, stream>>>(rgb_accum, acc_ws, out);
}